// Round 5
// baseline (340.693 us; speedup 1.0000x reference)
//
#include <hip/hip_runtime.h>

#define N_  8
#define C_  3
#define HD_ 1024
#define WD_ 1280
#define HS_ 800
#define WS_ 1280

typedef _Float16 h2_t __attribute__((ext_vector_type(2)));
typedef float f32x4 __attribute__((ext_vector_type(4)));

__device__ __forceinline__ unsigned pack_h2(float a, float b) {
    h2_t h;
    h.x = (_Float16)a;
    h.y = (_Float16)b;
    return __builtin_bit_cast(unsigned, h);
}
__device__ __forceinline__ h2_t as_h2(unsigned u) {
    return __builtin_bit_cast(h2_t, u);
}
__device__ __forceinline__ float fdot2(h2_t a, h2_t b, float c) {
#if __has_builtin(__builtin_amdgcn_fdot2)
    return __builtin_amdgcn_fdot2(a, b, c, false);
#else
    return (float)a.x * (float)b.x + (float)a.y * (float)b.y + c;
#endif
}

// ---------- pass 1: src [N,3,HS,WS] fp32 -> [N,HS,WS] 16B x-pair entries ----
// entry(x) = { h2(c0[x],c0[x+1]), h2(c1[x],c1[x+1]), h2(c2[x],c2[x+1]), 0 }
// with x+1 clamped at the row end (border fold baked into the table).
// 4 px/thread: aligned float4 read per channel + one 4B neighbor read (L1 hit).
__global__ __launch_bounds__(256) void pair_pack_kernel(
    const float* __restrict__ src, uint4* __restrict__ ws)
{
    const size_t HWs = (size_t)HS_ * WS_;
    size_t t = (size_t)blockIdx.x * blockDim.x + threadIdx.x;
    size_t base = t * 4;
    if (base >= (size_t)N_ * HWs) return;
    int n = (int)(base / HWs);
    size_t p = base - (size_t)n * HWs;
    int x = (int)(p % WS_);             // multiple of 4; WS_ % 4 == 0

    const float* s0 = src + (size_t)n * C_ * HWs + p;
    const float* s1 = s0 + HWs;
    const float* s2 = s1 + HWs;

    f32x4 c0 = *(const f32x4*)s0;
    f32x4 c1 = *(const f32x4*)s1;
    f32x4 c2 = *(const f32x4*)s2;
    int nxt = (x + 4 < WS_) ? 4 : 3;    // clamp pair partner at row end
    float e0 = s0[nxt], e1 = s1[nxt], e2 = s2[nxt];

    float c0v[5] = { c0[0], c0[1], c0[2], c0[3], e0 };
    float c1v[5] = { c1[0], c1[1], c1[2], c1[3], e1 };
    float c2v[5] = { c2[0], c2[1], c2[2], c2[3], e2 };

    uint4* o = ws + base;
#pragma unroll
    for (int j = 0; j < 4; ++j) {
        uint4 e;
        e.x = pack_h2(c0v[j], c0v[j + 1]);
        e.y = pack_h2(c1v[j], c1v[j + 1]);
        e.z = pack_h2(c2v[j], c2v[j + 1]);
        e.w = 0u;
        o[j] = e;
    }
}

// ---------- pass 2: warp + bilinear, 1 px/thread, 2 aligned 16B gathers ----
__global__ __launch_bounds__(256) void warp_main_kernel(
    const float* __restrict__ depth,   // [N,1,HD,WD]
    const uint4* __restrict__ wsrc,    // [N,HS,WS] 16B pair entries
    const float* __restrict__ abc,     // [3,HD,WD]
    const float* __restrict__ tr,      // [3]
    const float* __restrict__ pin,     // [4]
    float* __restrict__ out)           // [N,C,HD,WD]
{
    const int HW = HD_ * WD_;

    // XCD swizzle: route image k's blocks to XCD k so each XCD's L2 holds one
    // image's gather window instead of all 8 XCDs thrashing the same region.
    int bid = blockIdx.x;
    if ((gridDim.x & 7) == 0) {
        int per = gridDim.x >> 3;
        bid = (bid & 7) * per + (bid >> 3);
    }

    int idx = bid * blockDim.x + threadIdx.x;
    if (idx >= N_ * HW) return;

    int n  = idx / HW;
    int hw = idx - n * HW;

    float d = depth[idx];
    float a = abc[hw];
    float b = abc[HW + hw];
    float c = abc[2 * HW + hw];

    float tx = tr[0], ty = tr[1], tz = tr[2];
    float fu = pin[0], fv = pin[1], du = pin[2], dv = pin[3];

    float denom = c * d + tz;
    float inv = 1.0f / denom;
    float xx = (a * d + tx) * inv;
    float yy = (b * d + ty) * inv;
    float uu = fu * xx + du;
    float vv = fv * yy + dv;

    float gx = 2.0f * uu / (float)(WS_ - 1) - 1.0f;
    float gy = 2.0f * vv / (float)(HS_ - 1) - 1.0f;
    float x = ((gx + 1.0f) * (float)WS_ - 1.0f) * 0.5f;
    float y = ((gy + 1.0f) * (float)HS_ - 1.0f) * 0.5f;

    x = fminf(fmaxf(x, 0.0f), (float)(WS_ - 1));
    y = fminf(fmaxf(y, 0.0f), (float)(HS_ - 1));

    float x0f = floorf(x);
    float y0f = floorf(y);
    float wx = x - x0f;
    float wy = y - y0f;
    int x0 = (int)x0f;
    int y0 = (int)y0f;
    int y1 = min(y0 + 1, HS_ - 1);

    const size_t HWs = (size_t)HS_ * WS_;
    const uint4* sn = wsrc + (size_t)n * HWs;

    uint4 E0 = sn[(size_t)y0 * WS_ + x0];   // row y0: both x taps, 3 channels
    uint4 E1 = sn[(size_t)y1 * WS_ + x0];   // row y1

    h2_t wA = { (_Float16)(1.0f - wx), (_Float16)wx };
    float iwy = 1.0f - wy;

    float v0 = iwy * fdot2(as_h2(E0.x), wA, 0.0f) + wy * fdot2(as_h2(E1.x), wA, 0.0f);
    float v1 = iwy * fdot2(as_h2(E0.y), wA, 0.0f) + wy * fdot2(as_h2(E1.y), wA, 0.0f);
    float v2 = iwy * fdot2(as_h2(E0.z), wA, 0.0f) + wy * fdot2(as_h2(E1.z), wA, 0.0f);

    float* on = out + (size_t)n * C_ * HW + hw;
    __builtin_nontemporal_store(v0, on);
    __builtin_nontemporal_store(v1, on + (size_t)HW);
    __builtin_nontemporal_store(v2, on + (size_t)2 * HW);
}

// ---------- fallback: planar (no workspace needed) ----------
__global__ __launch_bounds__(256) void warp_planar_kernel(
    const float* __restrict__ depth, const float* __restrict__ src,
    const float* __restrict__ abc, const float* __restrict__ tr,
    const float* __restrict__ pin, float* __restrict__ out)
{
    const int HW = HD_ * WD_;
    int idx = blockIdx.x * blockDim.x + threadIdx.x;
    if (idx >= N_ * HW) return;
    int n  = idx / HW;
    int hw = idx - n * HW;
    float d = depth[idx];
    float a = abc[hw];
    float b = abc[HW + hw];
    float c = abc[2 * HW + hw];
    float denom = c * d + tr[2];
    float inv = 1.0f / denom;
    float uu = pin[0] * ((a * d + tr[0]) * inv) + pin[2];
    float vv = pin[1] * ((b * d + tr[1]) * inv) + pin[3];
    float gx = 2.0f * uu / (float)(WS_ - 1) - 1.0f;
    float gy = 2.0f * vv / (float)(HS_ - 1) - 1.0f;
    float x = ((gx + 1.0f) * (float)WS_ - 1.0f) * 0.5f;
    float y = ((gy + 1.0f) * (float)HS_ - 1.0f) * 0.5f;
    x = fminf(fmaxf(x, 0.0f), (float)(WS_ - 1));
    y = fminf(fmaxf(y, 0.0f), (float)(HS_ - 1));
    float x0f = floorf(x), y0f = floorf(y);
    float wx = x - x0f, wy = y - y0f;
    int x0 = (int)x0f, y0 = (int)y0f;
    int x1 = min(x0 + 1, WS_ - 1);
    int y1 = min(y0 + 1, HS_ - 1);
    float w00 = (1.0f - wy) * (1.0f - wx), w01 = (1.0f - wy) * wx;
    float w10 = wy * (1.0f - wx), w11 = wy * wx;
    const size_t HWs = (size_t)HS_ * WS_;
    const float* sn = src + (size_t)n * C_ * HWs;
    int o00 = y0 * WS_ + x0, o01 = y0 * WS_ + x1;
    int o10 = y1 * WS_ + x0, o11 = y1 * WS_ + x1;
    float* on = out + (size_t)n * C_ * HW + hw;
#pragma unroll
    for (int ch = 0; ch < C_; ++ch) {
        const float* sc = sn + (size_t)ch * HWs;
        on[(size_t)ch * HW] = sc[o00] * w00 + sc[o01] * w01
                            + sc[o10] * w10 + sc[o11] * w11;
    }
}

extern "C" void kernel_launch(void* const* d_in, const int* in_sizes, int n_in,
                              void* d_out, int out_size, void* d_ws, size_t ws_size,
                              hipStream_t stream) {
    const float* depth = (const float*)d_in[0];
    const float* src   = (const float*)d_in[1];
    const float* abc   = (const float*)d_in[2];
    const float* tr    = (const float*)d_in[3];
    const float* pin   = (const float*)d_in[4];
    float* out = (float*)d_out;

    const size_t src_px = (size_t)N_ * HS_ * WS_;
    const size_t need = src_px * 16;  // 16B per pair entry
    const int total = N_ * HD_ * WD_;
    const int block = 256;

    if (ws_size >= need) {
        const int g1 = (int)((src_px / 4 + block - 1) / block);
        pair_pack_kernel<<<g1, block, 0, stream>>>(src, (uint4*)d_ws);
        const int g2 = (total + block - 1) / block;
        warp_main_kernel<<<g2, block, 0, stream>>>(depth, (const uint4*)d_ws,
                                                   abc, tr, pin, out);
    } else {
        const int g = (total + block - 1) / block;
        warp_planar_kernel<<<g, block, 0, stream>>>(depth, src, abc, tr, pin, out);
    }
}